// Round 7
// baseline (340.164 us; speedup 1.0000x reference)
//
#include <hip/hip_runtime.h>

// Problem dims (fixed by the reference)
#define BB 8
#define SS 512
#define DD 768
#define LL 4096
#define MM (BB * SS)   // 4096 rows of H flattened

using v8bf  = __attribute__((ext_vector_type(8))) __bf16;
using f32x4 = __attribute__((ext_vector_type(4))) float;

typedef __attribute__((address_space(1))) void gvoid;  // global
typedef __attribute__((address_space(3))) void svoid;  // LDS

// ---- bf16 helpers (raw ushort storage)
static __device__ __forceinline__ unsigned short f2bf(float f) {
    unsigned int u = __float_as_uint(f);
    u = u + 0x7FFFu + ((u >> 16) & 1u);   // round-to-nearest-even
    return (unsigned short)(u >> 16);
}
static __device__ __forceinline__ float bf2f(unsigned short h) {
    return __uint_as_float(((unsigned int)h) << 16);
}

// ---------------------------------------------------------------------------
// f32 -> bf16 cast, vectorized x4. n4 = n/4.
// ---------------------------------------------------------------------------
__global__ __launch_bounds__(256) void cvt_bf16(
    const float* __restrict__ in, unsigned short* __restrict__ out, int n4)
{
    const int i = blockIdx.x * 256 + threadIdx.x;
    if (i < n4) {
        const float4 v = ((const float4*)in)[i];
        ushort4 o;
        o.x = f2bf(v.x); o.y = f2bf(v.y); o.z = f2bf(v.z); o.w = f2bf(v.w);
        ((ushort4*)out)[i] = o;
    }
}

// ---------------------------------------------------------------------------
// W_att [k][n] f32  ->  out [n][k] bf16   (768x768). 32x32 LDS tile transpose.
// ---------------------------------------------------------------------------
__global__ __launch_bounds__(256) void transpose_cvt(
    const float* __restrict__ in, unsigned short* __restrict__ out)
{
    __shared__ float t[32][33];
    const int x = blockIdx.x * 32 + threadIdx.x;   // input col (n)
    const int y0 = blockIdx.y * 32;                // input row (k)
    for (int i = threadIdx.y; i < 32; i += 8)
        t[i][threadIdx.x] = in[(size_t)(y0 + i) * DD + x];
    __syncthreads();
    const int xo = blockIdx.y * 32 + threadIdx.x;  // output col (k)
    const int yo0 = blockIdx.x * 32;               // output row (n)
    for (int i = threadIdx.y; i < 32; i += 8)
        out[(size_t)(yo0 + i) * DD + xo] = f2bf(t[threadIdx.x][i]);
}

// ---------------------------------------------------------------------------
// NT MFMA GEMM: C[M,N](bf16) = A[M,K=768](bf16) * B[N,K=768](bf16)^T
// 128x128 tile, BK=32, 256 threads = 4 waves in 2x2 quadrants, 4x4 16x16
// fragments per wave, mfma_f32_16x16x32_bf16, f32 accum.
// Staging: global_load_lds width=16 (m97 structure). LDS linear [128][32]:
// per call, lane l writes LDS base+l*16 <=> row=base/64+l/4, chunk=l%4 —
// matches per-lane global addr (srow=lane>>2, schk=lane&3). Base is
// wave-uniform (m104 constraint satisfied).
// EPI=0: C = bf16(acc).  EPI=1: C = bf16(tanh(acc + bias[n])).
// Frag layouts (HW-verified, learn_hip m89/m91): A/B row|col=lane&15,
// k=(lane>>4)*8+j; C/D col=lane&15, row=(lane>>4)*4+reg.
// ---------------------------------------------------------------------------
template <int EPI>
__global__ __launch_bounds__(256) void gemm_nt_mfma(
    const unsigned short* __restrict__ A,
    const unsigned short* __restrict__ B,
    const float* __restrict__ bias,
    unsigned short* __restrict__ C, int N)
{
    __shared__ __align__(16) unsigned short As[128 * 32];
    __shared__ __align__(16) unsigned short Bs[128 * 32];

    const int tid  = threadIdx.x;
    const int wid  = tid >> 6;
    const int lane = tid & 63;
    const int wr = wid >> 1, wc = wid & 1;          // wave quadrant (2x2 of 64x64)
    const int bm = blockIdx.y * 128, bn = blockIdx.x * 128;

    const int srow = lane >> 2;      // staging row within 16-row slab
    const int schk = lane & 3;       // 16B chunk within 64B row

    f32x4 acc[4][4];
#pragma unroll
    for (int m = 0; m < 4; ++m)
#pragma unroll
        for (int n = 0; n < 4; ++n)
            acc[m][n] = (f32x4){0.f, 0.f, 0.f, 0.f};

    const int fr = lane & 15;        // fragment row/col
    const int kg = lane >> 4;        // k-group (8 bf16 each)

    for (int kt = 0; kt < DD; kt += 32) {
        __syncthreads();   // all waves done reading LDS of previous tile
#pragma unroll
        for (int t = 0; t < 2; ++t) {
            const int row0 = (wid * 2 + t) * 16;           // wave-uniform
            const unsigned short* ga =
                A + (size_t)(bm + row0 + srow) * DD + kt + schk * 8;
            const unsigned short* gb =
                B + (size_t)(bn + row0 + srow) * DD + kt + schk * 8;
            __builtin_amdgcn_global_load_lds((gvoid*)ga, (svoid*)&As[row0 * 32], 16, 0, 0);
            __builtin_amdgcn_global_load_lds((gvoid*)gb, (svoid*)&Bs[row0 * 32], 16, 0, 0);
        }
        __syncthreads();   // drains vmcnt -> LDS tile ready

        v8bf af[4], bf[4];
#pragma unroll
        for (int m = 0; m < 4; ++m)
            af[m] = *reinterpret_cast<const v8bf*>(&As[(wr * 64 + m * 16 + fr) * 32 + kg * 8]);
#pragma unroll
        for (int n = 0; n < 4; ++n)
            bf[n] = *reinterpret_cast<const v8bf*>(&Bs[(wc * 64 + n * 16 + fr) * 32 + kg * 8]);
#pragma unroll
        for (int m = 0; m < 4; ++m)
#pragma unroll
            for (int n = 0; n < 4; ++n)
                acc[m][n] = __builtin_amdgcn_mfma_f32_16x16x32_bf16(
                    af[m], bf[n], acc[m][n], 0, 0, 0);
    }

    // epilogue
#pragma unroll
    for (int m = 0; m < 4; ++m) {
        const int gr0 = bm + wr * 64 + m * 16 + (lane >> 4) * 4;
#pragma unroll
        for (int n = 0; n < 4; ++n) {
            const int gc = bn + wc * 64 + n * 16 + (lane & 15);
            float bv = 0.f;
            if (EPI == 1) bv = bias[gc];
#pragma unroll
            for (int r = 0; r < 4; ++r) {
                float v = acc[m][n][r];
                if (EPI == 1) v = tanhf(v + bv);
                C[(size_t)(gr0 + r) * N + gc] = f2bf(v);
            }
        }
    }
}

// ---------------------------------------------------------------------------
// Fused softmax-over-S + HW-weighted reduce + bias + sigmoid.
// One thread per (b,l). Reads scores[b,s,l] / HW[b,s,l] coalesced across l.
// ---------------------------------------------------------------------------
__global__ __launch_bounds__(256) void pool_sigmoid(
    const unsigned short* __restrict__ scores,
    const unsigned short* __restrict__ HW,
    const float* __restrict__ b_out, float* __restrict__ out)
{
    const int l = blockIdx.x * 256 + threadIdx.x;
    const int b = blockIdx.y;
    const unsigned short* sp = scores + (size_t)b * SS * LL + l;
    const unsigned short* hp = HW + (size_t)b * SS * LL + l;

    float m = -1e30f;
#pragma unroll 8
    for (int s = 0; s < SS; ++s)
        m = fmaxf(m, bf2f(sp[(size_t)s * LL]));

    float den = 0.f, num = 0.f;
#pragma unroll 4
    for (int s = 0; s < SS; ++s) {
        const float e = __expf(bf2f(sp[(size_t)s * LL]) - m);
        den += e;
        num = fmaf(e, bf2f(hp[(size_t)s * LL]), num);
    }
    const float logit = num / den + b_out[l];
    out[(size_t)b * LL + l] = 1.f / (1.f + __expf(-logit));
}

// ---------------------------------------------------------------------------
extern "C" void kernel_launch(void* const* d_in, const int* in_sizes, int n_in,
                              void* d_out, int out_size, void* d_ws, size_t ws_size,
                              hipStream_t stream) {
    const float* H         = (const float*)d_in[0];
    const float* label_emb = (const float*)d_in[1];
    const float* W_att     = (const float*)d_in[2];
    const float* b_att     = (const float*)d_in[3];
    const float* W_out     = (const float*)d_in[4];
    const float* b_out     = (const float*)d_in[5];
    float* out = (float*)d_out;

    // ws layout (79.7 MB peak, X-region reuse):
    //   [scores bf16 33.5MB][Hbf 6.3MB][Wob 6.3MB][X 33.5MB]
    //   X holds Aatt(6.3) | Lbf(6.3) | Wab(1.2) until GEMM2; then HW overlays X.
    char* ws = (char*)d_ws;
    unsigned short* scores = (unsigned short*)ws;                       // 33,554,432
    unsigned short* Hbf    = (unsigned short*)(ws + 33554432);          //  6,291,456
    unsigned short* Wob    = (unsigned short*)(ws + 33554432 + 6291456);
    char* X = ws + 33554432 + 2 * 6291456;
    unsigned short* Aatt = (unsigned short*)X;                          //  6,291,456
    unsigned short* Lbf  = (unsigned short*)(X + 6291456);              //  6,291,456
    unsigned short* Wab  = (unsigned short*)(X + 2 * 6291456);          //  1,179,648
    unsigned short* HWp  = (unsigned short*)X;                          // 33,554,432 (after Aatt/Lbf/Wab dead)

    const dim3 blk(256);
    // prep: bf16 casts + W_att transpose
    cvt_bf16<<<dim3((MM * DD / 4 + 255) / 256), blk, 0, stream>>>(H, Hbf, MM * DD / 4);
    cvt_bf16<<<dim3((LL * DD / 4 + 255) / 256), blk, 0, stream>>>(label_emb, Lbf, LL * DD / 4);
    cvt_bf16<<<dim3((LL * DD / 4 + 255) / 256), blk, 0, stream>>>(W_out, Wob, LL * DD / 4);
    transpose_cvt<<<dim3(DD / 32, DD / 32), dim3(32, 8), 0, stream>>>(W_att, Wab);

    // 1) Aatt = tanh(Hbf @ Wab^T + b_att)      [4096,768] bf16
    gemm_nt_mfma<1><<<dim3(DD / 128, MM / 128), blk, 0, stream>>>(Hbf, Wab, b_att, Aatt, DD);
    // 2) scores = Aatt @ Lbf^T                 [4096,4096] bf16
    gemm_nt_mfma<0><<<dim3(LL / 128, MM / 128), blk, 0, stream>>>(Aatt, Lbf, nullptr, scores, LL);
    // 3) HW = Hbf @ Wob^T                      [4096,4096] bf16 (overlays X)
    gemm_nt_mfma<0><<<dim3(LL / 128, MM / 128), blk, 0, stream>>>(Hbf, Wob, nullptr, HWp, LL);
    // 4) softmax over s + weighted reduce + bias + sigmoid -> out [B,L]
    pool_sigmoid<<<dim3(LL / 256, BB), blk, 0, stream>>>(scores, HWp, b_out, out);
}

// Round 10
// 240.620 us; speedup vs baseline: 1.4137x; 1.4137x over previous
//
#include <hip/hip_runtime.h>

// Problem dims (fixed by the reference)
#define BB 8
#define SS 512
#define DD 768
#define LL 4096
#define MM (BB * SS)   // 4096 rows of H flattened

using v8bf  = __attribute__((ext_vector_type(8))) __bf16;
using f32x4 = __attribute__((ext_vector_type(4))) float;

typedef __attribute__((address_space(1))) void gvoid;  // global
typedef __attribute__((address_space(3))) void svoid;  // LDS

// ---- bf16 helpers (raw ushort storage)
static __device__ __forceinline__ unsigned short f2bf(float f) {
    unsigned int u = __float_as_uint(f);
    u = u + 0x7FFFu + ((u >> 16) & 1u);   // round-to-nearest-even
    return (unsigned short)(u >> 16);
}
static __device__ __forceinline__ float bf2f(unsigned short h) {
    return __uint_as_float(((unsigned int)h) << 16);
}

// ---------------------------------------------------------------------------
// f32 -> bf16 cast, vectorized x4. n4 = n/4.
// ---------------------------------------------------------------------------
__global__ __launch_bounds__(256) void cvt_bf16(
    const float* __restrict__ in, unsigned short* __restrict__ out, int n4)
{
    const int i = blockIdx.x * 256 + threadIdx.x;
    if (i < n4) {
        const float4 v = ((const float4*)in)[i];
        ushort4 o;
        o.x = f2bf(v.x); o.y = f2bf(v.y); o.z = f2bf(v.z); o.w = f2bf(v.w);
        ((ushort4*)out)[i] = o;
    }
}

// ---------------------------------------------------------------------------
// W_att [k][n] f32  ->  out [n][k] bf16   (768x768). 32x32 LDS tile transpose.
// ---------------------------------------------------------------------------
__global__ __launch_bounds__(256) void transpose_cvt(
    const float* __restrict__ in, unsigned short* __restrict__ out)
{
    __shared__ float t[32][33];
    const int x = blockIdx.x * 32 + threadIdx.x;   // input col (n)
    const int y0 = blockIdx.y * 32;                // input row (k)
    for (int i = threadIdx.y; i < 32; i += 8)
        t[i][threadIdx.x] = in[(size_t)(y0 + i) * DD + x];
    __syncthreads();
    const int xo = blockIdx.y * 32 + threadIdx.x;  // output col (k)
    const int yo0 = blockIdx.x * 32;               // output row (n)
    for (int i = threadIdx.y; i < 32; i += 8)
        out[(size_t)(yo0 + i) * DD + xo] = f2bf(t[threadIdx.x][i]);
}

// ---------------------------------------------------------------------------
// NT MFMA GEMM: C[M,N](bf16) = A[M,K=768](bf16) * B[N,K=768](bf16)^T
// 128x128 tile, BK=32, 256 threads = 4 waves in 2x2 quadrants, 4x4 16x16
// fragments per wave, mfma_f32_16x16x32_bf16, f32 accum.
// Staging: global_load_lds width=16 (m97 structure). LDS linear [128][32].
// EPI=0: C = bf16(acc).  EPI=1: C = bf16(tanh(acc + bias[n])).
// ---------------------------------------------------------------------------
template <int EPI>
__global__ __launch_bounds__(256) void gemm_nt_mfma(
    const unsigned short* __restrict__ A,
    const unsigned short* __restrict__ B,
    const float* __restrict__ bias,
    unsigned short* __restrict__ C, int N)
{
    __shared__ __align__(16) unsigned short As[128 * 32];
    __shared__ __align__(16) unsigned short Bs[128 * 32];

    const int tid  = threadIdx.x;
    const int wid  = tid >> 6;
    const int lane = tid & 63;
    const int wr = wid >> 1, wc = wid & 1;          // wave quadrant (2x2 of 64x64)
    const int bm = blockIdx.y * 128, bn = blockIdx.x * 128;

    const int srow = lane >> 2;      // staging row within 16-row slab
    const int schk = lane & 3;       // 16B chunk within 64B row

    f32x4 acc[4][4];
#pragma unroll
    for (int m = 0; m < 4; ++m)
#pragma unroll
        for (int n = 0; n < 4; ++n)
            acc[m][n] = (f32x4){0.f, 0.f, 0.f, 0.f};

    const int fr = lane & 15;        // fragment row/col
    const int kg = lane >> 4;        // k-group (8 bf16 each)

    for (int kt = 0; kt < DD; kt += 32) {
        __syncthreads();   // all waves done reading LDS of previous tile
#pragma unroll
        for (int t = 0; t < 2; ++t) {
            const int row0 = (wid * 2 + t) * 16;           // wave-uniform
            const unsigned short* ga =
                A + (size_t)(bm + row0 + srow) * DD + kt + schk * 8;
            const unsigned short* gb =
                B + (size_t)(bn + row0 + srow) * DD + kt + schk * 8;
            __builtin_amdgcn_global_load_lds((gvoid*)ga, (svoid*)&As[row0 * 32], 16, 0, 0);
            __builtin_amdgcn_global_load_lds((gvoid*)gb, (svoid*)&Bs[row0 * 32], 16, 0, 0);
        }
        __syncthreads();   // drains vmcnt -> LDS tile ready

        v8bf af[4], bf[4];
#pragma unroll
        for (int m = 0; m < 4; ++m)
            af[m] = *reinterpret_cast<const v8bf*>(&As[(wr * 64 + m * 16 + fr) * 32 + kg * 8]);
#pragma unroll
        for (int n = 0; n < 4; ++n)
            bf[n] = *reinterpret_cast<const v8bf*>(&Bs[(wc * 64 + n * 16 + fr) * 32 + kg * 8]);
#pragma unroll
        for (int m = 0; m < 4; ++m)
#pragma unroll
            for (int n = 0; n < 4; ++n)
                acc[m][n] = __builtin_amdgcn_mfma_f32_16x16x32_bf16(
                    af[m], bf[n], acc[m][n], 0, 0, 0);
    }

    // epilogue
#pragma unroll
    for (int m = 0; m < 4; ++m) {
        const int gr0 = bm + wr * 64 + m * 16 + (lane >> 4) * 4;
#pragma unroll
        for (int n = 0; n < 4; ++n) {
            const int gc = bn + wc * 64 + n * 16 + (lane & 15);
            float bv = 0.f;
            if (EPI == 1) bv = bias[gc];
#pragma unroll
            for (int r = 0; r < 4; ++r) {
                float v = acc[m][n][r];
                if (EPI == 1) v = tanhf(v + bv);
                C[(size_t)(gr0 + r) * N + gc] = f2bf(v);
            }
        }
    }
}

// ---------------------------------------------------------------------------
// Fused softmax-over-S + HW-weighted reduce + bias + sigmoid.
// s-parallel: block = 64 l-values x 4 s-groups (256 thr), grid (L/64, B)
// = 512 blocks. Lanes span consecutive l -> one 128B coalesced transaction
// per wave load. Cross-sgroup combine via LDS. (R7: 1-thread-per-(b,l) was
// 128 blocks, Occupancy 5.4%, 334 GB/s -> latency-bound at 145 us.)
// ---------------------------------------------------------------------------
__global__ __launch_bounds__(256) void pool_sigmoid(
    const unsigned short* __restrict__ scores,
    const unsigned short* __restrict__ HW,
    const float* __restrict__ b_out, float* __restrict__ out)
{
    __shared__ float red[3][4][64];
    const int lidx = threadIdx.x & 63;
    const int sg   = threadIdx.x >> 6;      // 0..3
    const int l0 = blockIdx.x * 64;
    const int b  = blockIdx.y;
    const size_t base = (size_t)b * SS * LL + l0 + lidx;
    const unsigned short* sp = scores + base;
    const unsigned short* hp = HW + base;

    // pass 1: max over this sgroup's s-subset
    float m = -1e30f;
#pragma unroll 8
    for (int s = sg; s < SS; s += 4)
        m = fmaxf(m, bf2f(sp[(size_t)s * LL]));
    red[0][sg][lidx] = m;
    __syncthreads();
    m = fmaxf(fmaxf(red[0][0][lidx], red[0][1][lidx]),
              fmaxf(red[0][2][lidx], red[0][3][lidx]));

    // pass 2: exp-sum and HW-weighted sum
    float den = 0.f, num = 0.f;
#pragma unroll 8
    for (int s = sg; s < SS; s += 4) {
        const float e = __expf(bf2f(sp[(size_t)s * LL]) - m);
        den += e;
        num = fmaf(e, bf2f(hp[(size_t)s * LL]), num);
    }
    red[1][sg][lidx] = den;
    red[2][sg][lidx] = num;
    __syncthreads();
    if (sg == 0) {
        den = red[1][0][lidx] + red[1][1][lidx] + red[1][2][lidx] + red[1][3][lidx];
        num = red[2][0][lidx] + red[2][1][lidx] + red[2][2][lidx] + red[2][3][lidx];
        const float logit = num / den + b_out[l0 + lidx];
        out[(size_t)b * LL + l0 + lidx] = 1.f / (1.f + __expf(-logit));
    }
}

// ---------------------------------------------------------------------------
extern "C" void kernel_launch(void* const* d_in, const int* in_sizes, int n_in,
                              void* d_out, int out_size, void* d_ws, size_t ws_size,
                              hipStream_t stream) {
    const float* H         = (const float*)d_in[0];
    const float* label_emb = (const float*)d_in[1];
    const float* W_att     = (const float*)d_in[2];
    const float* b_att     = (const float*)d_in[3];
    const float* W_out     = (const float*)d_in[4];
    const float* b_out     = (const float*)d_in[5];
    float* out = (float*)d_out;

    // ws layout (79.7 MB peak, X-region reuse):
    //   [scores bf16 33.5MB][Hbf 6.3MB][Wob 6.3MB][X 33.5MB]
    //   X holds Aatt(6.3) | Lbf(6.3) | Wab(1.2) until GEMM2; then HW overlays X.
    char* ws = (char*)d_ws;
    unsigned short* scores = (unsigned short*)ws;                       // 33,554,432
    unsigned short* Hbf    = (unsigned short*)(ws + 33554432);          //  6,291,456
    unsigned short* Wob    = (unsigned short*)(ws + 33554432 + 6291456);
    char* X = ws + 33554432 + 2 * 6291456;
    unsigned short* Aatt = (unsigned short*)X;                          //  6,291,456
    unsigned short* Lbf  = (unsigned short*)(X + 6291456);              //  6,291,456
    unsigned short* Wab  = (unsigned short*)(X + 2 * 6291456);          //  1,179,648
    unsigned short* HWp  = (unsigned short*)X;                          // 33,554,432 (after Aatt/Lbf/Wab dead)

    const dim3 blk(256);
    // prep: bf16 casts + W_att transpose
    cvt_bf16<<<dim3((MM * DD / 4 + 255) / 256), blk, 0, stream>>>(H, Hbf, MM * DD / 4);
    cvt_bf16<<<dim3((LL * DD / 4 + 255) / 256), blk, 0, stream>>>(label_emb, Lbf, LL * DD / 4);
    cvt_bf16<<<dim3((LL * DD / 4 + 255) / 256), blk, 0, stream>>>(W_out, Wob, LL * DD / 4);
    transpose_cvt<<<dim3(DD / 32, DD / 32), dim3(32, 8), 0, stream>>>(W_att, Wab);

    // 1) Aatt = tanh(Hbf @ Wab^T + b_att)      [4096,768] bf16
    gemm_nt_mfma<1><<<dim3(DD / 128, MM / 128), blk, 0, stream>>>(Hbf, Wab, b_att, Aatt, DD);
    // 2) scores = Aatt @ Lbf^T                 [4096,4096] bf16
    gemm_nt_mfma<0><<<dim3(LL / 128, MM / 128), blk, 0, stream>>>(Aatt, Lbf, nullptr, scores, LL);
    // 3) HW = Hbf @ Wob^T                      [4096,4096] bf16 (overlays X)
    gemm_nt_mfma<0><<<dim3(LL / 128, MM / 128), blk, 0, stream>>>(Hbf, Wob, nullptr, HWp, LL);
    // 4) softmax over s + weighted reduce + bias + sigmoid -> out [B,L]
    pool_sigmoid<<<dim3(LL / 64, BB), blk, 0, stream>>>(scores, HWp, b_out, out);
}

// Round 15
// 232.560 us; speedup vs baseline: 1.4627x; 1.0347x over previous
//
#include <hip/hip_runtime.h>

// Problem dims (fixed by the reference)
#define BB 8
#define SS 512
#define DD 768
#define LL 4096
#define MM (BB * SS)   // 4096 rows of H flattened

using v8bf  = __attribute__((ext_vector_type(8))) __bf16;
using f32x4 = __attribute__((ext_vector_type(4))) float;

typedef __attribute__((address_space(1))) void gvoid;  // global
typedef __attribute__((address_space(3))) void svoid;  // LDS

// ---- bf16 helpers (raw ushort storage)
static __device__ __forceinline__ unsigned short f2bf(float f) {
    unsigned int u = __float_as_uint(f);
    u = u + 0x7FFFu + ((u >> 16) & 1u);   // round-to-nearest-even
    return (unsigned short)(u >> 16);
}
static __device__ __forceinline__ float bf2f(unsigned short h) {
    return __uint_as_float(((unsigned int)h) << 16);
}

// ---------------------------------------------------------------------------
// f32 -> bf16 cast, vectorized x4. n4 = n/4.
// ---------------------------------------------------------------------------
__global__ __launch_bounds__(256) void cvt_bf16(
    const float* __restrict__ in, unsigned short* __restrict__ out, int n4)
{
    const int i = blockIdx.x * 256 + threadIdx.x;
    if (i < n4) {
        const float4 v = ((const float4*)in)[i];
        ushort4 o;
        o.x = f2bf(v.x); o.y = f2bf(v.y); o.z = f2bf(v.z); o.w = f2bf(v.w);
        ((ushort4*)out)[i] = o;
    }
}

// ---------------------------------------------------------------------------
// W_att [k][n] f32  ->  out [n][k] bf16   (768x768). 32x32 LDS tile transpose.
// ---------------------------------------------------------------------------
__global__ __launch_bounds__(256) void transpose_cvt(
    const float* __restrict__ in, unsigned short* __restrict__ out)
{
    __shared__ float t[32][33];
    const int x = blockIdx.x * 32 + threadIdx.x;   // input col (n)
    const int y0 = blockIdx.y * 32;                // input row (k)
    for (int i = threadIdx.y; i < 32; i += 8)
        t[i][threadIdx.x] = in[(size_t)(y0 + i) * DD + x];
    __syncthreads();
    const int xo = blockIdx.y * 32 + threadIdx.x;  // output col (k)
    const int yo0 = blockIdx.x * 32;               // output row (n)
    for (int i = threadIdx.y; i < 32; i += 8)
        out[(size_t)(yo0 + i) * DD + xo] = f2bf(t[threadIdx.x][i]);
}

// ---------------------------------------------------------------------------
// NT MFMA GEMM: C[M,N](bf16) = A[M,K=768](bf16) * B[N,K=768](bf16)^T
// 128x128 tile, BK=64 (R11: was 32 -> halves barrier/vmcnt-drain count),
// 256 threads = 4 waves in 2x2 quadrants, mfma_f32_16x16x32_bf16.
// LDS [128][64] bf16 = 128B rows, T2 XOR-swizzle: logical k-slot s (16B)
// of row r stored at phys slot s^(r&7). gload_lds dest stays LINEAR (m104);
// the per-lane GLOBAL source carries the involution (m173 pattern):
// lane l covers row=slab+(l>>3), phys slot l&7 -> loads logical slot
// (l&7)^(l>>3). Reads XOR with fr&7 -> 8 bank-quads, 2 lanes each = free.
// (R10 counters: [128][32] linear had 8-way conflicts, 3.1M cycles/disp.)
// EPI=0: C = bf16(acc).  EPI=1: C = bf16(tanh(acc + bias[n])).
// ---------------------------------------------------------------------------
template <int EPI>
__global__ __launch_bounds__(256) void gemm_nt_mfma(
    const unsigned short* __restrict__ A,
    const unsigned short* __restrict__ B,
    const float* __restrict__ bias,
    unsigned short* __restrict__ C, int N)
{
    __shared__ __align__(16) unsigned short As[128 * 64];
    __shared__ __align__(16) unsigned short Bs[128 * 64];

    const int tid  = threadIdx.x;
    const int wid  = tid >> 6;
    const int lane = tid & 63;
    const int wr = wid >> 1, wc = wid & 1;          // wave quadrant (2x2 of 64x64)
    const int bm = blockIdx.y * 128, bn = blockIdx.x * 128;

    // staging: slab = 8 rows = 1024B per gload_lds. lane l -> row slab+(l>>3),
    // 16B chunk (l&7); source slot pre-swizzled so linear LDS dest lands the
    // swizzled layout.
    const int lrow  = lane >> 3;
    const int lslot = (lane & 7) ^ lrow;

    f32x4 acc[4][4];
#pragma unroll
    for (int m = 0; m < 4; ++m)
#pragma unroll
        for (int n = 0; n < 4; ++n)
            acc[m][n] = (f32x4){0.f, 0.f, 0.f, 0.f};

    const int fr = lane & 15;        // fragment row/col
    const int kg = lane >> 4;        // k-group (8 bf16 each)

    for (int kt = 0; kt < DD; kt += 64) {
        __syncthreads();   // all waves done reading LDS of previous tile
#pragma unroll
        for (int t = 0; t < 4; ++t) {
            const int row0 = (wid * 4 + t) * 8;            // wave-uniform slab
            const unsigned short* ga =
                A + (size_t)(bm + row0 + lrow) * DD + kt + lslot * 8;
            const unsigned short* gb =
                B + (size_t)(bn + row0 + lrow) * DD + kt + lslot * 8;
            __builtin_amdgcn_global_load_lds((gvoid*)ga, (svoid*)&As[row0 * 64], 16, 0, 0);
            __builtin_amdgcn_global_load_lds((gvoid*)gb, (svoid*)&Bs[row0 * 64], 16, 0, 0);
        }
        __syncthreads();   // drains vmcnt -> LDS tile ready

#pragma unroll
        for (int kk = 0; kk < 2; ++kk) {
            v8bf af[4], bf[4];
#pragma unroll
            for (int m = 0; m < 4; ++m) {
                const int r = wr * 64 + m * 16 + fr;
                af[m] = *reinterpret_cast<const v8bf*>(
                    &As[r * 64 + (((kk * 4 + kg) ^ (fr & 7)) * 8)]);
            }
#pragma unroll
            for (int n = 0; n < 4; ++n) {
                const int r = wc * 64 + n * 16 + fr;
                bf[n] = *reinterpret_cast<const v8bf*>(
                    &Bs[r * 64 + (((kk * 4 + kg) ^ (fr & 7)) * 8)]);
            }
#pragma unroll
            for (int m = 0; m < 4; ++m)
#pragma unroll
                for (int n = 0; n < 4; ++n)
                    acc[m][n] = __builtin_amdgcn_mfma_f32_16x16x32_bf16(
                        af[m], bf[n], acc[m][n], 0, 0, 0);
        }
    }

    // epilogue
#pragma unroll
    for (int m = 0; m < 4; ++m) {
        const int gr0 = bm + wr * 64 + m * 16 + (lane >> 4) * 4;
#pragma unroll
        for (int n = 0; n < 4; ++n) {
            const int gc = bn + wc * 64 + n * 16 + (lane & 15);
            float bv = 0.f;
            if (EPI == 1) bv = bias[gc];
#pragma unroll
            for (int r = 0; r < 4; ++r) {
                float v = acc[m][n][r];
                if (EPI == 1) v = tanhf(v + bv);
                C[(size_t)(gr0 + r) * N + gc] = f2bf(v);
            }
        }
    }
}

// ---------------------------------------------------------------------------
// Fused softmax-over-S + HW-weighted reduce + bias + sigmoid.
// s-parallel: block = 64 l-values x 4 s-groups (256 thr), grid (L/64, B)
// = 512 blocks. (R10: dropped out of top-5, was 145us at R7.)
// ---------------------------------------------------------------------------
__global__ __launch_bounds__(256) void pool_sigmoid(
    const unsigned short* __restrict__ scores,
    const unsigned short* __restrict__ HW,
    const float* __restrict__ b_out, float* __restrict__ out)
{
    __shared__ float red[3][4][64];
    const int lidx = threadIdx.x & 63;
    const int sg   = threadIdx.x >> 6;      // 0..3
    const int l0 = blockIdx.x * 64;
    const int b  = blockIdx.y;
    const size_t base = (size_t)b * SS * LL + l0 + lidx;
    const unsigned short* sp = scores + base;
    const unsigned short* hp = HW + base;

    // pass 1: max over this sgroup's s-subset
    float m = -1e30f;
#pragma unroll 8
    for (int s = sg; s < SS; s += 4)
        m = fmaxf(m, bf2f(sp[(size_t)s * LL]));
    red[0][sg][lidx] = m;
    __syncthreads();
    m = fmaxf(fmaxf(red[0][0][lidx], red[0][1][lidx]),
              fmaxf(red[0][2][lidx], red[0][3][lidx]));

    // pass 2: exp-sum and HW-weighted sum
    float den = 0.f, num = 0.f;
#pragma unroll 8
    for (int s = sg; s < SS; s += 4) {
        const float e = __expf(bf2f(sp[(size_t)s * LL]) - m);
        den += e;
        num = fmaf(e, bf2f(hp[(size_t)s * LL]), num);
    }
    red[1][sg][lidx] = den;
    red[2][sg][lidx] = num;
    __syncthreads();
    if (sg == 0) {
        den = red[1][0][lidx] + red[1][1][lidx] + red[1][2][lidx] + red[1][3][lidx];
        num = red[2][0][lidx] + red[2][1][lidx] + red[2][2][lidx] + red[2][3][lidx];
        const float logit = num / den + b_out[l0 + lidx];
        out[(size_t)b * LL + l0 + lidx] = 1.f / (1.f + __expf(-logit));
    }
}

// ---------------------------------------------------------------------------
extern "C" void kernel_launch(void* const* d_in, const int* in_sizes, int n_in,
                              void* d_out, int out_size, void* d_ws, size_t ws_size,
                              hipStream_t stream) {
    const float* H         = (const float*)d_in[0];
    const float* label_emb = (const float*)d_in[1];
    const float* W_att     = (const float*)d_in[2];
    const float* b_att     = (const float*)d_in[3];
    const float* W_out     = (const float*)d_in[4];
    const float* b_out     = (const float*)d_in[5];
    float* out = (float*)d_out;

    // ws layout (79.7 MB peak, X-region reuse):
    //   [scores bf16 33.5MB][Hbf 6.3MB][Wob 6.3MB][X 33.5MB]
    //   X holds Aatt(6.3) | Lbf(6.3) | Wab(1.2) until GEMM2; then HW overlays X.
    char* ws = (char*)d_ws;
    unsigned short* scores = (unsigned short*)ws;                       // 33,554,432
    unsigned short* Hbf    = (unsigned short*)(ws + 33554432);          //  6,291,456
    unsigned short* Wob    = (unsigned short*)(ws + 33554432 + 6291456);
    char* X = ws + 33554432 + 2 * 6291456;
    unsigned short* Aatt = (unsigned short*)X;                          //  6,291,456
    unsigned short* Lbf  = (unsigned short*)(X + 6291456);              //  6,291,456
    unsigned short* Wab  = (unsigned short*)(X + 2 * 6291456);          //  1,179,648
    unsigned short* HWp  = (unsigned short*)X;                          // 33,554,432 (after Aatt/Lbf/Wab dead)

    const dim3 blk(256);
    // prep: bf16 casts + W_att transpose
    cvt_bf16<<<dim3((MM * DD / 4 + 255) / 256), blk, 0, stream>>>(H, Hbf, MM * DD / 4);
    cvt_bf16<<<dim3((LL * DD / 4 + 255) / 256), blk, 0, stream>>>(label_emb, Lbf, LL * DD / 4);
    cvt_bf16<<<dim3((LL * DD / 4 + 255) / 256), blk, 0, stream>>>(W_out, Wob, LL * DD / 4);
    transpose_cvt<<<dim3(DD / 32, DD / 32), dim3(32, 8), 0, stream>>>(W_att, Wab);

    // 1) Aatt = tanh(Hbf @ Wab^T + b_att)      [4096,768] bf16
    gemm_nt_mfma<1><<<dim3(DD / 128, MM / 128), blk, 0, stream>>>(Hbf, Wab, b_att, Aatt, DD);
    // 2) scores = Aatt @ Lbf^T                 [4096,4096] bf16
    gemm_nt_mfma<0><<<dim3(LL / 128, MM / 128), blk, 0, stream>>>(Aatt, Lbf, nullptr, scores, LL);
    // 3) HW = Hbf @ Wob^T                      [4096,4096] bf16 (overlays X)
    gemm_nt_mfma<0><<<dim3(LL / 128, MM / 128), blk, 0, stream>>>(Hbf, Wob, nullptr, HWp, LL);
    // 4) softmax over s + weighted reduce + bias + sigmoid -> out [B,L]
    pool_sigmoid<<<dim3(LL / 64, BB), blk, 0, stream>>>(scores, HWp, b_out, out);
}